// Round 2
// baseline (1635.130 us; speedup 1.0000x reference)
//
#include <hip/hip_runtime.h>

// ---- problem constants ----
#define D_IN  200
#define HDIM  1024
#define OUTN  1095
#define LNUM  12
#define BB    128
#define TT    20
#define MROWS (BB * TT)  // 2560

typedef __bf16 bf16;
typedef __attribute__((ext_vector_type(8))) __bf16 bf16x8;
typedef __attribute__((ext_vector_type(4))) float floatx4;

// ---- GEMM tile config ----
#define BM 64
#define BN 64
#define BK 32
#define LDSP (BK + 8)

// dtype codes: 0 = bf16, 1 = fp32, 2 = follow detected input dtype
__device__ __forceinline__ bool res_f32(int dt, int inf32) {
  return dt == 1 || (dt == 2 && inf32 != 0);
}

// Detect input dtype from W1's raw words. bf16 data: low 16 bits of each word
// are a real weight (~N(0,0.07)) -> exponent in [104,131] nearly always.
// fp32 data: low 16 bits are random mantissa -> ~11% hit rate.
__global__ __launch_bounds__(64) void detect_k(const unsigned int* __restrict__ w,
                                               int* __restrict__ flag) {
  int cnt = 0;
  for (int i = threadIdx.x; i < 1024; i += 64) {
    unsigned int ex = (w[i] >> 7) & 0xFFu;
    if (ex >= 104u && ex <= 131u) cnt++;
  }
  #pragma unroll
  for (int off = 32; off; off >>= 1) cnt += __shfl_down(cnt, off);
  if (threadIdx.x == 0) *flag = (cnt > 512) ? 0 : 1;  // 1 => inputs are fp32
}

// C = A(remapped rows) @ B + bias ; optional out1 = bf16(relu(C)) (ws, bf16)
__global__ __launch_bounds__(256) void gemm_k(
    const void* __restrict__ A, const void* __restrict__ Bm,
    const void* __restrict__ bias,
    void* __restrict__ out0, unsigned long long out0_eoff, int o0_dt,
    bf16* __restrict__ out1,
    const int* __restrict__ dflag,
    unsigned long long b_eoff, unsigned long long bias_eoff,
    int M, int N, int K, int remapP, int remapQ, int a_dt)
{
  __shared__ bf16 As[BM][LDSP];
  __shared__ bf16 Bs[BN][LDSP];  // transposed: Bs[n][k]

  const int inf32 = *dflag;
  const bool af32 = res_f32(a_dt, inf32);
  const bool bf32 = (inf32 != 0);
  const bool o0f  = res_f32(o0_dt, inf32);

  const int tid = threadIdx.x;
  const int bm = blockIdx.x * BM;
  const int bn = blockIdx.y * BN;

  const int a_r = tid >> 2;
  const int a_k = (tid & 3) * 8;
  int a_row = bm + a_r;
  const bool a_ok = a_row < M;
  if (remapP) a_row = (a_row % remapP) * remapQ + (a_row / remapP);
  const size_t a_off = (size_t)a_row * (size_t)K;

  const int b_k = tid >> 3;
  const int b_ng = bn + (tid & 7) * 8;
  const int b_nl = (tid & 7) * 8;
  const bool n_vec = ((N & 7) == 0) && (b_ng + 8 <= N);

  const int wave = tid >> 6;
  const int lane = tid & 63;
  const int wm = (wave >> 1) * 32;
  const int wn = (wave & 1) * 32;
  const int lm = lane & 15;
  const int q  = lane >> 4;

  floatx4 acc00 = {0.f,0.f,0.f,0.f}, acc01 = {0.f,0.f,0.f,0.f};
  floatx4 acc10 = {0.f,0.f,0.f,0.f}, acc11 = {0.f,0.f,0.f,0.f};

  for (int k0 = 0; k0 < K; k0 += BK) {
    // ---- stage A tile ----
    {
      union { bf16x8 v; bf16 e[8]; } av;
      const int kg = k0 + a_k;
      if (af32) {
        const float* Af = (const float*)A;
        if (a_ok && (kg + 8 <= K)) {
          floatx4 f0 = *(const floatx4*)(Af + a_off + kg);
          floatx4 f1 = *(const floatx4*)(Af + a_off + kg + 4);
          #pragma unroll
          for (int e = 0; e < 4; e++) { av.e[e] = (bf16)f0[e]; av.e[4 + e] = (bf16)f1[e]; }
        } else {
          #pragma unroll
          for (int e = 0; e < 8; e++) {
            const int kk = kg + e;
            av.e[e] = (a_ok && kk < K) ? (bf16)Af[a_off + kk] : (bf16)0.f;
          }
        }
      } else {
        const bf16* Ab = (const bf16*)A;
        if (a_ok && (kg + 8 <= K)) {
          av.v = *(const bf16x8*)(Ab + a_off + kg);
        } else {
          #pragma unroll
          for (int e = 0; e < 8; e++) {
            const int kk = kg + e;
            av.e[e] = (a_ok && kk < K) ? Ab[a_off + kk] : (bf16)0.f;
          }
        }
      }
      *(bf16x8*)&As[a_r][a_k] = av.v;
    }
    // ---- stage B tile (transpose into LDS) ----
    {
      union { bf16x8 v; bf16 e[8]; } bv;
      const int kg = k0 + b_k;
      if (bf32) {
        const float* Bf = (const float*)Bm + b_eoff;
        if ((kg < K) && n_vec) {
          floatx4 f0 = *(const floatx4*)(Bf + (size_t)kg * N + b_ng);
          floatx4 f1 = *(const floatx4*)(Bf + (size_t)kg * N + b_ng + 4);
          #pragma unroll
          for (int e = 0; e < 4; e++) { bv.e[e] = (bf16)f0[e]; bv.e[4 + e] = (bf16)f1[e]; }
        } else {
          #pragma unroll
          for (int e = 0; e < 8; e++) {
            const int nn = b_ng + e;
            bv.e[e] = (kg < K && nn < N) ? (bf16)Bf[(size_t)kg * N + nn] : (bf16)0.f;
          }
        }
      } else {
        const bf16* Bb = (const bf16*)Bm + b_eoff;
        if ((kg < K) && n_vec) {
          bv.v = *(const bf16x8*)(Bb + (size_t)kg * N + b_ng);
        } else {
          #pragma unroll
          for (int e = 0; e < 8; e++) {
            const int nn = b_ng + e;
            bv.e[e] = (kg < K && nn < N) ? Bb[(size_t)kg * N + nn] : (bf16)0.f;
          }
        }
      }
      #pragma unroll
      for (int e = 0; e < 8; e++) Bs[b_nl + e][b_k] = bv.e[e];
    }
    __syncthreads();

    const bf16x8 a0 = *(const bf16x8*)&As[wm + lm][q * 8];
    const bf16x8 a1 = *(const bf16x8*)&As[wm + 16 + lm][q * 8];
    const bf16x8 b0 = *(const bf16x8*)&Bs[wn + lm][q * 8];
    const bf16x8 b1 = *(const bf16x8*)&Bs[wn + 16 + lm][q * 8];
    acc00 = __builtin_amdgcn_mfma_f32_16x16x32_bf16(a0, b0, acc00, 0, 0, 0);
    acc01 = __builtin_amdgcn_mfma_f32_16x16x32_bf16(a0, b1, acc01, 0, 0, 0);
    acc10 = __builtin_amdgcn_mfma_f32_16x16x32_bf16(a1, b0, acc10, 0, 0, 0);
    acc11 = __builtin_amdgcn_mfma_f32_16x16x32_bf16(a1, b1, acc11, 0, 0, 0);
    __syncthreads();
  }

  // ---- epilogue: C[row = q*4+reg, col = lane&15] per 16x16 subtile ----
  floatx4 accs[2][2] = {{acc00, acc01}, {acc10, acc11}};
  const int r0 = bm + wm + q * 4;
  const int c0 = bn + wn + lm;
  #pragma unroll
  for (int i = 0; i < 2; i++) {
    #pragma unroll
    for (int j = 0; j < 2; j++) {
      const int c = c0 + j * 16;
      if (c >= N) continue;
      float bias_v = 0.f;
      if (bias) {
        bias_v = inf32 ? ((const float*)bias)[bias_eoff + c]
                       : (float)((const bf16*)bias)[bias_eoff + c];
      }
      #pragma unroll
      for (int reg = 0; reg < 4; reg++) {
        const int r = r0 + i * 16 + reg;
        if (r >= M) continue;
        const float v = accs[i][j][reg] + bias_v;
        const size_t o = (size_t)r * (size_t)N + c;
        if (o0f) ((float*)out0)[out0_eoff + o] = v;
        else     ((bf16*)out0)[out0_eoff + o] = (bf16)v;
        if (out1) out1[o] = (bf16)(v > 0.f ? v : 0.f);
      }
    }
  }
}

__device__ __forceinline__ float sigmoidf_(float x) { return 1.f / (1.f + __expf(-x)); }
__device__ __forceinline__ float tanhf_(float x)    { return 1.f - 2.f / (__expf(2.f * x) + 1.f); }

// One thread per (b,h) chain; serial over T=20. h updated IN PLACE (thread-private chain).
__global__ __launch_bounds__(256) void sru_scan_k(
    const void* __restrict__ U, int u_f32,
    bf16* __restrict__ h,                       // [T,B,H] in-place
    const void* __restrict__ c0, unsigned long long c0_eoff,
    const void* __restrict__ bvec, unsigned long long bvec_eoff,
    const int* __restrict__ dflag,
    void* __restrict__ cout, unsigned long long cout_eoff)
{
  const int inf32 = *dflag;
  const int idx = blockIdx.x * 256 + threadIdx.x;  // b*H + h
  const int hh = idx & (HDIM - 1);
  const int b = idx >> 10;
  const float bf_ = inf32 ? ((const float*)bvec)[bvec_eoff + hh]
                          : (float)((const bf16*)bvec)[bvec_eoff + hh];
  const float br_ = inf32 ? ((const float*)bvec)[bvec_eoff + HDIM + hh]
                          : (float)((const bf16*)bvec)[bvec_eoff + HDIM + hh];
  float c = inf32 ? ((const float*)c0)[c0_eoff + idx]
                  : (float)((const bf16*)c0)[c0_eoff + idx];
  const float* Uf = (const float*)U;
  const bf16*  Ub = (const bf16*)U;
  #pragma unroll 4
  for (int t = 0; t < TT; t++) {
    const size_t off = (size_t)(t * BB + b) * (size_t)(3 * HDIM);
    const float xt = u_f32 ? Uf[off + hh] : (float)Ub[off + hh];
    const float fp = u_f32 ? Uf[off + HDIM + hh] : (float)Ub[off + HDIM + hh];
    const float rp = u_f32 ? Uf[off + 2 * HDIM + hh] : (float)Ub[off + 2 * HDIM + hh];
    const float fg = sigmoidf_(fp + bf_);
    const float rg = sigmoidf_(rp + br_);
    c = fg * c + (1.f - fg) * xt;
    const size_t hi = (size_t)t * (BB * HDIM) + idx;
    const float xin = (float)h[hi];
    h[hi] = (bf16)(rg * tanhf_(c) + (1.f - rg) * xin);
  }
  if (inf32) ((float*)cout)[cout_eoff + idx] = c;
  else       ((bf16*)cout)[cout_eoff + idx] = (bf16)c;
}

extern "C" void kernel_launch(void* const* d_in, const int* in_sizes, int n_in,
                              void* d_out, int out_size, void* d_ws, size_t ws_size,
                              hipStream_t stream) {
  const void* x       = d_in[0];
  const void* hidden0 = d_in[1];
  const void* W1      = d_in[2];
  const void* b1      = d_in[3];
  const void* sru_W   = d_in[4];
  const void* sru_b   = d_in[5];
  const void* W3      = d_in[6];
  const void* b3      = d_in[7];
  const void* W4      = d_in[8];
  const void* b4      = d_in[9];

  // element offsets into d_out (dtype resolved on device)
  const unsigned long long eo_logits = 0ull;
  const unsigned long long eo_fx     = (unsigned long long)MROWS * OUTN;
  const unsigned long long eo_hid    = eo_fx + (unsigned long long)MROWS * HDIM;

  int* dflag = (int*)d_ws;
  char* ws = (char*)d_ws + 256;
  bf16* hA = (bf16*)ws;                                   // [T*B, H] bf16: 5.24 MB
  char* Ubase = ws + (size_t)MROWS * HDIM * 2;
  const size_t need_f32U = 256 + (size_t)MROWS * HDIM * 2 + (size_t)MROWS * 3 * HDIM * 4;
  const int u_f32 = (ws_size >= need_f32U) ? 1 : 0;       // fp32 U if ws allows (31.5 MB) else bf16
  void* U = (void*)Ubase;
  bf16* y = (bf16*)Ubase;  // aliases U; y live only after all U uses are done

  dim3 blk(256);

  detect_k<<<1, 64, 0, stream>>>((const unsigned int*)W1, dflag);

  // h = x @ W1 + b1, rows remapped (b,t)->(t,b); out bf16 ws
  gemm_k<<<dim3(MROWS / BM, HDIM / BN), blk, 0, stream>>>(
      x, W1, b1, hA, 0ull, 0, nullptr, dflag, 0ull, 0ull,
      MROWS, HDIM, D_IN, BB, TT, 2);

  for (int l = 0; l < LNUM; l++) {
    gemm_k<<<dim3(MROWS / BM, (3 * HDIM) / BN), blk, 0, stream>>>(
        hA, sru_W, nullptr, U, 0ull, (u_f32 ? 1 : 0), nullptr, dflag,
        (unsigned long long)l * HDIM * 3 * HDIM, 0ull,
        MROWS, 3 * HDIM, HDIM, 0, 0, 0);
    sru_scan_k<<<dim3((BB * HDIM) / 256), blk, 0, stream>>>(
        U, u_f32, hA,
        hidden0, (unsigned long long)l * BB * HDIM,
        sru_b,   (unsigned long long)l * 2 * HDIM,
        dflag, d_out, eo_hid + (unsigned long long)l * BB * HDIM);
  }

  // fx = h @ W3 + b3 (rows remapped (t,b)->(b,t)) -> d_out; y = relu(fx) bf16 ws
  gemm_k<<<dim3(MROWS / BM, HDIM / BN), blk, 0, stream>>>(
      hA, W3, b3, d_out, eo_fx, 2, y, dflag, 0ull, 0ull,
      MROWS, HDIM, HDIM, TT, BB, 0);

  // logits = y @ W4 + b4 -> d_out
  gemm_k<<<dim3(MROWS / BM, (OUTN + BN - 1) / BN), blk, 0, stream>>>(
      y, W4, b4, d_out, eo_logits, 2, nullptr, dflag, 0ull, 0ull,
      MROWS, OUTN, HDIM, 0, 0, 0);
}

// Round 3
// 931.196 us; speedup vs baseline: 1.7559x; 1.7559x over previous
//
#include <hip/hip_runtime.h>

// ---- problem constants ----
#define D_IN  200
#define KPAD1 224   // D_IN padded to multiple of 32
#define HDIM  1024
#define OUTN  1095
#define NPAD4 1152  // OUTN padded to multiple of 128
#define LNUM  12
#define BB    128
#define TT    20
#define MROWS (BB * TT)  // 2560

typedef __bf16 bf16;
typedef __attribute__((ext_vector_type(8))) __bf16 bf16x8;
typedef __attribute__((ext_vector_type(4))) float floatx4;

// dtype codes: 0 = bf16, 1 = fp32, 2 = follow detected input dtype
__device__ __forceinline__ bool res_f32(int dt, int inf32) {
  return dt == 1 || (dt == 2 && inf32 != 0);
}

// Detect input dtype from W1's raw words (see R1 notes). flag=1 => fp32 inputs.
__global__ __launch_bounds__(64) void detect_k(const unsigned int* __restrict__ w,
                                               int* __restrict__ flag) {
  int cnt = 0;
  for (int i = threadIdx.x; i < 1024; i += 64) {
    unsigned int ex = (w[i] >> 7) & 0xFFu;
    if (ex >= 104u && ex <= 131u) cnt++;
  }
  #pragma unroll
  for (int off = 32; off; off >>= 1) cnt += __shfl_down(cnt, off);
  if (threadIdx.x == 0) *flag = (cnt > 512) ? 0 : 1;
}

// out[n][k] = (n<N && k<K) ? in[k][n] : 0, out is [Npad][Kpad] bf16, batched.
__global__ __launch_bounds__(256) void transp_k(
    const void* __restrict__ in, const int* __restrict__ dflag,
    bf16* __restrict__ out, int K, int N, int Kpad, int Npad,
    unsigned long long in_bs, unsigned long long out_bs)
{
  __shared__ float tile[32][33];
  const int inf32 = *dflag;
  const int tx = threadIdx.x & 31, ty = threadIdx.x >> 5;  // 32 x 8
  const int kt = blockIdx.x * 32, nt = blockIdx.y * 32;
  const float* inf = (const float*)in + (size_t)blockIdx.z * in_bs;
  const bf16*  inb = (const bf16*)in + (size_t)blockIdx.z * in_bs;
  #pragma unroll
  for (int j = 0; j < 4; j++) {
    const int k = kt + ty + j * 8, n = nt + tx;
    float v = 0.f;
    if (k < K && n < N)
      v = inf32 ? inf[(size_t)k * N + n] : (float)inb[(size_t)k * N + n];
    tile[ty + j * 8][tx] = v;
  }
  __syncthreads();
  bf16* o = out + (size_t)blockIdx.z * out_bs;
  #pragma unroll
  for (int j = 0; j < 4; j++) {
    const int n = nt + ty + j * 8, k = kt + tx;
    if (n < Npad && k < Kpad) o[(size_t)n * Kpad + k] = (bf16)tile[tx][ty + j * 8];
  }
}

// xc[t*B+b][0..KPAD1) <- x[b][t][0..D_IN) (zero-padded), bf16
__global__ __launch_bounds__(256) void convx_k(
    const void* __restrict__ x, const int* __restrict__ dflag, bf16* __restrict__ xc)
{
  const int inf32 = *dflag;
  const int idx = blockIdx.x * 256 + threadIdx.x;
  if (idx >= MROWS * KPAD1) return;
  const int row = idx / KPAD1;
  const int d = idx - row * KPAD1;
  const int t = row / BB, b = row - t * BB;
  float v = 0.f;
  if (d < D_IN) {
    const size_t src = ((size_t)b * TT + t) * D_IN + d;
    v = inf32 ? ((const float*)x)[src] : (float)((const bf16*)x)[src];
  }
  xc[idx] = (bf16)v;
}

// ---- fast GEMM (m97 structure): 128x128 tile, BK=32, global_load_lds staging.
// A [M,Ks] bf16 k-contig (rows optionally remapped), Bt [Npad,Ks] bf16 k-contig.
// M % 128 == 0, Ks % 32 == 0, Npad % 128 == 0 (zero rows beyond N).
__global__ __launch_bounds__(256) void gemm_f(
    const bf16* __restrict__ A, const bf16* __restrict__ Bt,
    const void* __restrict__ bias, unsigned long long bias_eoff,
    const int* __restrict__ dflag,
    void* __restrict__ out0, unsigned long long out0_eoff, int o0_dt,
    bf16* __restrict__ out1,
    int N, int Ks, int remapP, int remapQ)
{
  __shared__ bf16 As[128 * 32];
  __shared__ bf16 Bs[128 * 32];
  const int inf32 = *dflag;
  const bool o0f = res_f32(o0_dt, inf32);

  const int tid = threadIdx.x;
  const int wave = tid >> 6, lane = tid & 63;
  const int wr = wave >> 1, wc = wave & 1;
  const int lm = lane & 15, q = lane >> 4;
  const int l4r = lane >> 2, l4k = (lane & 3) * 8;

  const int bm = blockIdx.x * 128, bn = blockIdx.y * 128;

  // staging: wave w covers LDS rows [w*32, w*32+32), two 16-row instrs
  int ar0 = bm + wave * 32 + l4r;
  int ar1 = ar0 + 16;
  if (remapP) {
    ar0 = (ar0 % remapP) * remapQ + ar0 / remapP;
    ar1 = (ar1 % remapP) * remapQ + ar1 / remapP;
  }
  const bf16* gA0 = A + (size_t)ar0 * Ks + l4k;
  const bf16* gA1 = A + (size_t)ar1 * Ks + l4k;
  const bf16* gB0 = Bt + (size_t)(bn + wave * 32 + l4r) * Ks + l4k;
  const bf16* gB1 = gB0 + (size_t)16 * Ks;

  auto* As3 = (__attribute__((address_space(3))) char*)As;
  auto* Bs3 = (__attribute__((address_space(3))) char*)Bs;
  const int lds0 = (wave * 32) * 64;       // byte offset of this wave's 32-row span
  const int lds1 = lds0 + 16 * 64;

  floatx4 acc[4][4];
  #pragma unroll
  for (int i = 0; i < 4; i++)
    #pragma unroll
    for (int j = 0; j < 4; j++) acc[i][j] = (floatx4){0.f, 0.f, 0.f, 0.f};

  for (int k0 = 0; k0 < Ks; k0 += 32) {
    __builtin_amdgcn_global_load_lds((const __attribute__((address_space(1))) void*)gA0,
                                     (__attribute__((address_space(3))) void*)(As3 + lds0), 16, 0, 0);
    __builtin_amdgcn_global_load_lds((const __attribute__((address_space(1))) void*)gA1,
                                     (__attribute__((address_space(3))) void*)(As3 + lds1), 16, 0, 0);
    __builtin_amdgcn_global_load_lds((const __attribute__((address_space(1))) void*)gB0,
                                     (__attribute__((address_space(3))) void*)(Bs3 + lds0), 16, 0, 0);
    __builtin_amdgcn_global_load_lds((const __attribute__((address_space(1))) void*)gB1,
                                     (__attribute__((address_space(3))) void*)(Bs3 + lds1), 16, 0, 0);
    gA0 += 32; gA1 += 32; gB0 += 32; gB1 += 32;
    __syncthreads();

    bf16x8 af[4], bfr[4];
    #pragma unroll
    for (int mi = 0; mi < 4; mi++)
      af[mi] = *(const bf16x8*)&As[(wr * 64 + mi * 16 + lm) * 32 + q * 8];
    #pragma unroll
    for (int ni = 0; ni < 4; ni++)
      bfr[ni] = *(const bf16x8*)&Bs[(wc * 64 + ni * 16 + lm) * 32 + q * 8];
    #pragma unroll
    for (int mi = 0; mi < 4; mi++)
      #pragma unroll
      for (int ni = 0; ni < 4; ni++)
        acc[mi][ni] = __builtin_amdgcn_mfma_f32_16x16x32_bf16(af[mi], bfr[ni], acc[mi][ni], 0, 0, 0);
    __syncthreads();
  }

  // epilogue: row = q*4+reg, col = lane&15 per 16x16 subtile
  const int row_base = bm + wr * 64 + q * 4;
  const int col_base = bn + wc * 64 + lm;
  #pragma unroll
  for (int ni = 0; ni < 4; ni++) {
    const int c = col_base + ni * 16;
    if (c >= N) continue;
    float bv = 0.f;
    if (bias)
      bv = inf32 ? ((const float*)bias)[bias_eoff + c]
                 : (float)((const bf16*)bias)[bias_eoff + c];
    #pragma unroll
    for (int mi = 0; mi < 4; mi++)
      #pragma unroll
      for (int reg = 0; reg < 4; reg++) {
        const int r = row_base + mi * 16 + reg;
        const float v = acc[mi][ni][reg] + bv;
        const size_t o = (size_t)r * N + c;
        if (o0f) ((float*)out0)[out0_eoff + o] = v;
        else     ((bf16*)out0)[out0_eoff + o] = (bf16)v;
        if (out1) out1[o] = (bf16)(v > 0.f ? v : 0.f);
      }
  }
}

// ================= fallback generic GEMM (R1, proven) =================
#define BM 64
#define BN 64
#define BK 32
#define LDSP (BK + 8)

__global__ __launch_bounds__(256) void gemm_k(
    const void* __restrict__ A, const void* __restrict__ Bm,
    const void* __restrict__ bias,
    void* __restrict__ out0, unsigned long long out0_eoff, int o0_dt,
    bf16* __restrict__ out1,
    const int* __restrict__ dflag,
    unsigned long long b_eoff, unsigned long long bias_eoff,
    int M, int N, int K, int remapP, int remapQ, int a_dt)
{
  __shared__ bf16 As[BM][LDSP];
  __shared__ bf16 Bs[BN][LDSP];

  const int inf32 = *dflag;
  const bool af32 = res_f32(a_dt, inf32);
  const bool bf32 = (inf32 != 0);
  const bool o0f  = res_f32(o0_dt, inf32);

  const int tid = threadIdx.x;
  const int bm = blockIdx.x * BM;
  const int bn = blockIdx.y * BN;

  const int a_r = tid >> 2;
  const int a_k = (tid & 3) * 8;
  int a_row = bm + a_r;
  const bool a_ok = a_row < M;
  if (remapP) a_row = (a_row % remapP) * remapQ + (a_row / remapP);
  const size_t a_off = (size_t)a_row * (size_t)K;

  const int b_k = tid >> 3;
  const int b_ng = bn + (tid & 7) * 8;
  const int b_nl = (tid & 7) * 8;
  const bool n_vec = ((N & 7) == 0) && (b_ng + 8 <= N);

  const int wave = tid >> 6;
  const int lane = tid & 63;
  const int wm = (wave >> 1) * 32;
  const int wn = (wave & 1) * 32;
  const int lm = lane & 15;
  const int q  = lane >> 4;

  floatx4 acc00 = {0.f,0.f,0.f,0.f}, acc01 = {0.f,0.f,0.f,0.f};
  floatx4 acc10 = {0.f,0.f,0.f,0.f}, acc11 = {0.f,0.f,0.f,0.f};

  for (int k0 = 0; k0 < K; k0 += BK) {
    {
      union { bf16x8 v; bf16 e[8]; } av;
      const int kg = k0 + a_k;
      if (af32) {
        const float* Af = (const float*)A;
        if (a_ok && (kg + 8 <= K)) {
          floatx4 f0 = *(const floatx4*)(Af + a_off + kg);
          floatx4 f1 = *(const floatx4*)(Af + a_off + kg + 4);
          #pragma unroll
          for (int e = 0; e < 4; e++) { av.e[e] = (bf16)f0[e]; av.e[4 + e] = (bf16)f1[e]; }
        } else {
          #pragma unroll
          for (int e = 0; e < 8; e++) {
            const int kk = kg + e;
            av.e[e] = (a_ok && kk < K) ? (bf16)Af[a_off + kk] : (bf16)0.f;
          }
        }
      } else {
        const bf16* Ab = (const bf16*)A;
        if (a_ok && (kg + 8 <= K)) {
          av.v = *(const bf16x8*)(Ab + a_off + kg);
        } else {
          #pragma unroll
          for (int e = 0; e < 8; e++) {
            const int kk = kg + e;
            av.e[e] = (a_ok && kk < K) ? Ab[a_off + kk] : (bf16)0.f;
          }
        }
      }
      *(bf16x8*)&As[a_r][a_k] = av.v;
    }
    {
      union { bf16x8 v; bf16 e[8]; } bv;
      const int kg = k0 + b_k;
      if (bf32) {
        const float* Bf = (const float*)Bm + b_eoff;
        if ((kg < K) && n_vec) {
          floatx4 f0 = *(const floatx4*)(Bf + (size_t)kg * N + b_ng);
          floatx4 f1 = *(const floatx4*)(Bf + (size_t)kg * N + b_ng + 4);
          #pragma unroll
          for (int e = 0; e < 4; e++) { bv.e[e] = (bf16)f0[e]; bv.e[4 + e] = (bf16)f1[e]; }
        } else {
          #pragma unroll
          for (int e = 0; e < 8; e++) {
            const int nn = b_ng + e;
            bv.e[e] = (kg < K && nn < N) ? (bf16)Bf[(size_t)kg * N + nn] : (bf16)0.f;
          }
        }
      } else {
        const bf16* Bb = (const bf16*)Bm + b_eoff;
        if ((kg < K) && n_vec) {
          bv.v = *(const bf16x8*)(Bb + (size_t)kg * N + b_ng);
        } else {
          #pragma unroll
          for (int e = 0; e < 8; e++) {
            const int nn = b_ng + e;
            bv.e[e] = (kg < K && nn < N) ? Bb[(size_t)kg * N + nn] : (bf16)0.f;
          }
        }
      }
      #pragma unroll
      for (int e = 0; e < 8; e++) Bs[b_nl + e][b_k] = bv.e[e];
    }
    __syncthreads();

    const bf16x8 a0 = *(const bf16x8*)&As[wm + lm][q * 8];
    const bf16x8 a1 = *(const bf16x8*)&As[wm + 16 + lm][q * 8];
    const bf16x8 b0 = *(const bf16x8*)&Bs[wn + lm][q * 8];
    const bf16x8 b1 = *(const bf16x8*)&Bs[wn + 16 + lm][q * 8];
    acc00 = __builtin_amdgcn_mfma_f32_16x16x32_bf16(a0, b0, acc00, 0, 0, 0);
    acc01 = __builtin_amdgcn_mfma_f32_16x16x32_bf16(a0, b1, acc01, 0, 0, 0);
    acc10 = __builtin_amdgcn_mfma_f32_16x16x32_bf16(a1, b0, acc10, 0, 0, 0);
    acc11 = __builtin_amdgcn_mfma_f32_16x16x32_bf16(a1, b1, acc11, 0, 0, 0);
    __syncthreads();
  }

  floatx4 accs[2][2] = {{acc00, acc01}, {acc10, acc11}};
  const int r0 = bm + wm + q * 4;
  const int c0 = bn + wn + lm;
  #pragma unroll
  for (int i = 0; i < 2; i++) {
    #pragma unroll
    for (int j = 0; j < 2; j++) {
      const int c = c0 + j * 16;
      if (c >= N) continue;
      float bias_v = 0.f;
      if (bias) {
        bias_v = inf32 ? ((const float*)bias)[bias_eoff + c]
                       : (float)((const bf16*)bias)[bias_eoff + c];
      }
      #pragma unroll
      for (int reg = 0; reg < 4; reg++) {
        const int r = r0 + i * 16 + reg;
        if (r >= M) continue;
        const float v = accs[i][j][reg] + bias_v;
        const size_t o = (size_t)r * (size_t)N + c;
        if (o0f) ((float*)out0)[out0_eoff + o] = v;
        else     ((bf16*)out0)[out0_eoff + o] = (bf16)v;
        if (out1) out1[o] = (bf16)(v > 0.f ? v : 0.f);
      }
    }
  }
}

__device__ __forceinline__ float sigmoidf_(float x) { return 1.f / (1.f + __expf(-x)); }
__device__ __forceinline__ float tanhf_(float x)    { return 1.f - 2.f / (__expf(2.f * x) + 1.f); }

__global__ __launch_bounds__(256) void sru_scan_k(
    const void* __restrict__ U, int u_f32,
    bf16* __restrict__ h,
    const void* __restrict__ c0, unsigned long long c0_eoff,
    const void* __restrict__ bvec, unsigned long long bvec_eoff,
    const int* __restrict__ dflag,
    void* __restrict__ cout, unsigned long long cout_eoff)
{
  const int inf32 = *dflag;
  const int idx = blockIdx.x * 256 + threadIdx.x;
  const int hh = idx & (HDIM - 1);
  const int b = idx >> 10;
  const float bf_ = inf32 ? ((const float*)bvec)[bvec_eoff + hh]
                          : (float)((const bf16*)bvec)[bvec_eoff + hh];
  const float br_ = inf32 ? ((const float*)bvec)[bvec_eoff + HDIM + hh]
                          : (float)((const bf16*)bvec)[bvec_eoff + HDIM + hh];
  float c = inf32 ? ((const float*)c0)[c0_eoff + idx]
                  : (float)((const bf16*)c0)[c0_eoff + idx];
  const float* Uf = (const float*)U;
  const bf16*  Ub = (const bf16*)U;
  #pragma unroll 4
  for (int t = 0; t < TT; t++) {
    const size_t off = (size_t)(t * BB + b) * (size_t)(3 * HDIM);
    const float xt = u_f32 ? Uf[off + hh] : (float)Ub[off + hh];
    const float fp = u_f32 ? Uf[off + HDIM + hh] : (float)Ub[off + HDIM + hh];
    const float rp = u_f32 ? Uf[off + 2 * HDIM + hh] : (float)Ub[off + 2 * HDIM + hh];
    const float fg = sigmoidf_(fp + bf_);
    const float rg = sigmoidf_(rp + br_);
    c = fg * c + (1.f - fg) * xt;
    const size_t hi = (size_t)t * (BB * HDIM) + idx;
    const float xin = (float)h[hi];
    h[hi] = (bf16)(rg * tanhf_(c) + (1.f - rg) * xin);
  }
  if (inf32) ((float*)cout)[cout_eoff + idx] = c;
  else       ((bf16*)cout)[cout_eoff + idx] = (bf16)c;
}

extern "C" void kernel_launch(void* const* d_in, const int* in_sizes, int n_in,
                              void* d_out, int out_size, void* d_ws, size_t ws_size,
                              hipStream_t stream) {
  const void* x       = d_in[0];
  const void* hidden0 = d_in[1];
  const void* W1      = d_in[2];
  const void* b1      = d_in[3];
  const void* sru_W   = d_in[4];
  const void* sru_b   = d_in[5];
  const void* W3      = d_in[6];
  const void* b3      = d_in[7];
  const void* W4      = d_in[8];
  const void* b4      = d_in[9];

  const unsigned long long eo_fx  = (unsigned long long)MROWS * OUTN;
  const unsigned long long eo_hid = eo_fx + (unsigned long long)MROWS * HDIM;

  // ---- ws layout (fast path) ----
  const size_t z_flag = 256;
  const size_t z_hA   = (size_t)MROWS * HDIM * 2;          //  5.24 MB
  const size_t z_U    = (size_t)MROWS * 3 * HDIM * 4;      // 31.46 MB
  const size_t z_xc   = (size_t)MROWS * KPAD1 * 2;         //  1.15 MB
  const size_t z_W1T  = (size_t)HDIM * KPAD1 * 2;          //  0.46 MB
  const size_t z_sWT  = (size_t)LNUM * 3 * HDIM * HDIM * 2;// 75.50 MB
  const size_t z_W3T  = (size_t)HDIM * HDIM * 2;           //  2.10 MB
  const size_t z_W4T  = (size_t)NPAD4 * HDIM * 2;          //  2.36 MB
  const size_t FAST_NEED = z_flag + z_hA + z_U + z_xc + z_W1T + z_sWT + z_W3T + z_W4T;

  int* dflag = (int*)d_ws;
  char* p = (char*)d_ws + z_flag;
  bf16*  hA    = (bf16*)p;            p += z_hA;
  char*  Ubase = p;                   p += z_U;
  bf16*  xc    = (bf16*)p;            p += z_xc;
  bf16*  W1T   = (bf16*)p;            p += z_W1T;
  bf16*  sWT   = (bf16*)p;            p += z_sWT;
  bf16*  W3T   = (bf16*)p;            p += z_W3T;
  bf16*  W4T   = (bf16*)p;
  void*  U = (void*)Ubase;
  bf16*  y = (bf16*)Ubase;  // aliases U; live only after all U uses done

  dim3 blk(256);
  detect_k<<<1, 64, 0, stream>>>((const unsigned int*)W1, dflag);

  if (ws_size >= FAST_NEED) {
    // ---- conversion pass ----
    convx_k<<<dim3((MROWS * KPAD1 + 255) / 256), blk, 0, stream>>>(x, dflag, xc);
    transp_k<<<dim3(KPAD1 / 32, HDIM / 32, 1), blk, 0, stream>>>(
        W1, dflag, W1T, D_IN, HDIM, KPAD1, HDIM, 0ull, 0ull);
    transp_k<<<dim3(HDIM / 32, 3 * HDIM / 32, LNUM), blk, 0, stream>>>(
        sru_W, dflag, sWT, HDIM, 3 * HDIM, HDIM, 3 * HDIM,
        (unsigned long long)HDIM * 3 * HDIM, (unsigned long long)3 * HDIM * HDIM);
    transp_k<<<dim3(HDIM / 32, HDIM / 32, 1), blk, 0, stream>>>(
        W3, dflag, W3T, HDIM, HDIM, HDIM, HDIM, 0ull, 0ull);
    transp_k<<<dim3(HDIM / 32, NPAD4 / 32, 1), blk, 0, stream>>>(
        W4, dflag, W4T, HDIM, OUTN, HDIM, NPAD4, 0ull, 0ull);

    // ---- h = xc @ W1T + b1 -> hA (bf16, [T,B,H]) ----
    gemm_f<<<dim3(MROWS / 128, HDIM / 128), blk, 0, stream>>>(
        xc, W1T, b1, 0ull, dflag, hA, 0ull, 0, nullptr, HDIM, KPAD1, 0, 0);

    for (int l = 0; l < LNUM; l++) {
      gemm_f<<<dim3(MROWS / 128, 3 * HDIM / 128), blk, 0, stream>>>(
          hA, sWT + (size_t)l * 3 * HDIM * HDIM, nullptr, 0ull, dflag,
          U, 0ull, 1, nullptr, 3 * HDIM, HDIM, 0, 0);
      sru_scan_k<<<dim3((BB * HDIM) / 256), blk, 0, stream>>>(
          U, 1, hA, hidden0, (unsigned long long)l * BB * HDIM,
          sru_b, (unsigned long long)l * 2 * HDIM,
          dflag, d_out, eo_hid + (unsigned long long)l * BB * HDIM);
    }

    // fx = h @ W3 + b3 (rows remapped (t,b)->(b,t)); y = relu(fx)
    gemm_f<<<dim3(MROWS / 128, HDIM / 128), blk, 0, stream>>>(
        hA, W3T, b3, 0ull, dflag, d_out, eo_fx, 2, y, HDIM, HDIM, TT, BB);

    // logits = y @ W4 + b4
    gemm_f<<<dim3(MROWS / 128, NPAD4 / 128), blk, 0, stream>>>(
        y, W4T, b4, 0ull, dflag, d_out, 0ull, 2, nullptr, OUTN, HDIM, 0, 0);
  } else {
    // ---- fallback: R1 proven path (needs ~37 MB) ----
    const size_t need_f32U = z_flag + z_hA + z_U;
    const int u_f32 = (ws_size >= need_f32U) ? 1 : 0;

    gemm_k<<<dim3(MROWS / BM, HDIM / BN), blk, 0, stream>>>(
        x, W1, b1, hA, 0ull, 0, nullptr, dflag, 0ull, 0ull,
        MROWS, HDIM, D_IN, BB, TT, 2);

    for (int l = 0; l < LNUM; l++) {
      gemm_k<<<dim3(MROWS / BM, (3 * HDIM) / BN), blk, 0, stream>>>(
          hA, sru_W, nullptr, U, 0ull, (u_f32 ? 1 : 0), nullptr, dflag,
          (unsigned long long)l * HDIM * 3 * HDIM, 0ull,
          MROWS, 3 * HDIM, HDIM, 0, 0, 0);
      sru_scan_k<<<dim3((BB * HDIM) / 256), blk, 0, stream>>>(
          U, u_f32, hA, hidden0, (unsigned long long)l * BB * HDIM,
          sru_b, (unsigned long long)l * 2 * HDIM,
          dflag, d_out, eo_hid + (unsigned long long)l * BB * HDIM);
    }

    gemm_k<<<dim3(MROWS / BM, HDIM / BN), blk, 0, stream>>>(
        hA, W3, b3, d_out, eo_fx, 2, y, dflag, 0ull, 0ull,
        MROWS, HDIM, HDIM, TT, BB, 0);

    gemm_k<<<dim3(MROWS / BM, (OUTN + BN - 1) / BN), blk, 0, stream>>>(
        y, W4, b4, d_out, 0ull, 2, nullptr, dflag, 0ull, 0ull,
        MROWS, OUTN, HDIM, 0, 0, 0);
  }
}

// Round 5
// 846.137 us; speedup vs baseline: 1.9325x; 1.1005x over previous
//
#include <hip/hip_runtime.h>

// ---- problem constants ----
#define D_IN  200
#define KPAD1 224   // D_IN padded to multiple of 32
#define HDIM  1024
#define OUTN  1095
#define NPAD4 1152  // OUTN padded to multiple of 128
#define LNUM  12
#define BB    128
#define TT    20
#define MROWS (BB * TT)  // 2560

typedef __bf16 bf16;
typedef __attribute__((ext_vector_type(2))) __bf16 bf16x2;
typedef __attribute__((ext_vector_type(8))) __bf16 bf16x8;
typedef __attribute__((ext_vector_type(2))) float floatx2;
typedef __attribute__((ext_vector_type(4))) float floatx4;

// dtype codes: 0 = bf16, 1 = fp32, 2 = follow detected input dtype
__device__ __forceinline__ bool res_f32(int dt, int inf32) {
  return dt == 1 || (dt == 2 && inf32 != 0);
}

// Detect input dtype from W1's raw words. flag=1 => fp32 inputs.
__global__ __launch_bounds__(64) void detect_k(const unsigned int* __restrict__ w,
                                               int* __restrict__ flag) {
  int cnt = 0;
  for (int i = threadIdx.x; i < 1024; i += 64) {
    unsigned int ex = (w[i] >> 7) & 0xFFu;
    if (ex >= 104u && ex <= 131u) cnt++;
  }
  #pragma unroll
  for (int off = 32; off; off >>= 1) cnt += __shfl_down(cnt, off);
  if (threadIdx.x == 0) *flag = (cnt > 512) ? 0 : 1;
}

// ---- fast transpose: out[n][K] = in[k][n], K%64==0, Npad%64==0, batched ----
// fp32 LDS tile [64][69]: pad 69 => column reads (rows 16 apart) hit 32 banks (2-way, free).
__global__ __launch_bounds__(256) void ftransp_k(
    const void* __restrict__ in, const int* __restrict__ dflag,
    bf16* __restrict__ out, int K, int N, int Npad,
    unsigned long long in_bs, unsigned long long out_bs)
{
  __shared__ float tile[64][69];
  const int inf32 = *dflag;
  const int t = threadIdx.x;
  const int kt = blockIdx.x * 64, nt = blockIdx.y * 64;
  const float* inf = (const float*)in + (size_t)blockIdx.z * in_bs;
  const bf16*  inb = (const bf16*)in + (size_t)blockIdx.z * in_bs;

  const int lk = t >> 2;               // 0..63
  const size_t rbase = (size_t)(kt + lk) * N;
  #pragma unroll
  for (int j = 0; j < 4; j++) {
    const int ln = ((t & 3) + 4 * j) * 4;   // 0..60 step 4
    const int gn = nt + ln;
    floatx4 v = {0.f, 0.f, 0.f, 0.f};
    if (inf32) {
      if (gn + 4 <= N) {
        v = *(const floatx4*)(inf + rbase + gn);
      } else {
        #pragma unroll
        for (int e = 0; e < 4; e++) if (gn + e < N) v[e] = inf[rbase + gn + e];
      }
    } else {
      #pragma unroll
      for (int e = 0; e < 4; e++) if (gn + e < N) v[e] = (float)inb[rbase + gn + e];
    }
    #pragma unroll
    for (int e = 0; e < 4; e++) tile[lk][ln + e] = v[e];
  }
  __syncthreads();

  const int n  = t >> 2;               // 0..63
  const int kc = (t & 3) * 16;         // 0..48
  union { bf16x8 v[2]; bf16 e[16]; } o;
  #pragma unroll
  for (int i = 0; i < 16; i++) o.e[i] = (bf16)tile[kc + i][n];
  bf16* op = out + (size_t)blockIdx.z * out_bs + (size_t)(nt + n) * K + kt + kc;
  *(bf16x8*)op = o.v[0];
  *(bf16x8*)(op + 8) = o.v[1];
}

// small generic transpose (kept for W1: K=200 not %64)
__global__ __launch_bounds__(256) void transp_k(
    const void* __restrict__ in, const int* __restrict__ dflag,
    bf16* __restrict__ out, int K, int N, int Kpad, int Npad,
    unsigned long long in_bs, unsigned long long out_bs)
{
  __shared__ float tile[32][33];
  const int inf32 = *dflag;
  const int tx = threadIdx.x & 31, ty = threadIdx.x >> 5;
  const int kt = blockIdx.x * 32, nt = blockIdx.y * 32;
  const float* inf = (const float*)in + (size_t)blockIdx.z * in_bs;
  const bf16*  inb = (const bf16*)in + (size_t)blockIdx.z * in_bs;
  #pragma unroll
  for (int j = 0; j < 4; j++) {
    const int k = kt + ty + j * 8, n = nt + tx;
    float v = 0.f;
    if (k < K && n < N)
      v = inf32 ? inf[(size_t)k * N + n] : (float)inb[(size_t)k * N + n];
    tile[ty + j * 8][tx] = v;
  }
  __syncthreads();
  bf16* o = out + (size_t)blockIdx.z * out_bs;
  #pragma unroll
  for (int j = 0; j < 4; j++) {
    const int n = nt + ty + j * 8, k = kt + tx;
    if (n < Npad && k < Kpad) o[(size_t)n * Kpad + k] = (bf16)tile[tx][ty + j * 8];
  }
}

// xc[t*B+b][0..KPAD1) <- x[b][t][0..D_IN) (zero-padded), bf16
__global__ __launch_bounds__(256) void convx_k(
    const void* __restrict__ x, const int* __restrict__ dflag, bf16* __restrict__ xc)
{
  const int inf32 = *dflag;
  const int idx = blockIdx.x * 256 + threadIdx.x;
  if (idx >= MROWS * KPAD1) return;
  const int row = idx / KPAD1;
  const int d = idx - row * KPAD1;
  const int t = row / BB, b = row - t * BB;
  float v = 0.f;
  if (d < D_IN) {
    const size_t src = ((size_t)b * TT + t) * D_IN + d;
    v = inf32 ? ((const float*)x)[src] : (float)((const bf16*)x)[src];
  }
  xc[idx] = (bf16)v;
}

// ---- fast GEMM (m97 structure): 128x128 tile, BK=32, global_load_lds staging ----
__global__ __launch_bounds__(256) void gemm_f(
    const bf16* __restrict__ A, const bf16* __restrict__ Bt,
    const void* __restrict__ bias, unsigned long long bias_eoff,
    const int* __restrict__ dflag,
    void* __restrict__ out0, unsigned long long out0_eoff, int o0_dt,
    bf16* __restrict__ out1,
    int N, int Ks, int remapP, int remapQ)
{
  __shared__ bf16 As[128 * 32];
  __shared__ bf16 Bs[128 * 32];
  const int inf32 = *dflag;
  const bool o0f = res_f32(o0_dt, inf32);

  const int tid = threadIdx.x;
  const int wave = tid >> 6, lane = tid & 63;
  const int wr = wave >> 1, wc = wave & 1;
  const int lm = lane & 15, q = lane >> 4;
  const int l4r = lane >> 2, l4k = (lane & 3) * 8;

  const int bm = blockIdx.x * 128, bn = blockIdx.y * 128;

  int ar0 = bm + wave * 32 + l4r;
  int ar1 = ar0 + 16;
  if (remapP) {
    ar0 = (ar0 % remapP) * remapQ + ar0 / remapP;
    ar1 = (ar1 % remapP) * remapQ + ar1 / remapP;
  }
  const bf16* gA0 = A + (size_t)ar0 * Ks + l4k;
  const bf16* gA1 = A + (size_t)ar1 * Ks + l4k;
  const bf16* gB0 = Bt + (size_t)(bn + wave * 32 + l4r) * Ks + l4k;
  const bf16* gB1 = gB0 + (size_t)16 * Ks;

  auto* As3 = (__attribute__((address_space(3))) char*)As;
  auto* Bs3 = (__attribute__((address_space(3))) char*)Bs;
  const int lds0 = (wave * 32) * 64;
  const int lds1 = lds0 + 16 * 64;

  floatx4 acc[4][4];
  #pragma unroll
  for (int i = 0; i < 4; i++)
    #pragma unroll
    for (int j = 0; j < 4; j++) acc[i][j] = (floatx4){0.f, 0.f, 0.f, 0.f};

  for (int k0 = 0; k0 < Ks; k0 += 32) {
    __builtin_amdgcn_global_load_lds((const __attribute__((address_space(1))) void*)gA0,
                                     (__attribute__((address_space(3))) void*)(As3 + lds0), 16, 0, 0);
    __builtin_amdgcn_global_load_lds((const __attribute__((address_space(1))) void*)gA1,
                                     (__attribute__((address_space(3))) void*)(As3 + lds1), 16, 0, 0);
    __builtin_amdgcn_global_load_lds((const __attribute__((address_space(1))) void*)gB0,
                                     (__attribute__((address_space(3))) void*)(Bs3 + lds0), 16, 0, 0);
    __builtin_amdgcn_global_load_lds((const __attribute__((address_space(1))) void*)gB1,
                                     (__attribute__((address_space(3))) void*)(Bs3 + lds1), 16, 0, 0);
    gA0 += 32; gA1 += 32; gB0 += 32; gB1 += 32;
    __syncthreads();

    bf16x8 af[4], bfr[4];
    #pragma unroll
    for (int mi = 0; mi < 4; mi++)
      af[mi] = *(const bf16x8*)&As[(wr * 64 + mi * 16 + lm) * 32 + q * 8];
    #pragma unroll
    for (int ni = 0; ni < 4; ni++)
      bfr[ni] = *(const bf16x8*)&Bs[(wc * 64 + ni * 16 + lm) * 32 + q * 8];
    #pragma unroll
    for (int mi = 0; mi < 4; mi++)
      #pragma unroll
      for (int ni = 0; ni < 4; ni++)
        acc[mi][ni] = __builtin_amdgcn_mfma_f32_16x16x32_bf16(af[mi], bfr[ni], acc[mi][ni], 0, 0, 0);
    __syncthreads();
  }

  const int row_base = bm + wr * 64 + q * 4;
  const int col_base = bn + wc * 64 + lm;
  #pragma unroll
  for (int ni = 0; ni < 4; ni++) {
    const int c = col_base + ni * 16;
    if (c >= N) continue;
    float bv = 0.f;
    if (bias)
      bv = inf32 ? ((const float*)bias)[bias_eoff + c]
                 : (float)((const bf16*)bias)[bias_eoff + c];
    #pragma unroll
    for (int mi = 0; mi < 4; mi++)
      #pragma unroll
      for (int reg = 0; reg < 4; reg++) {
        const int r = row_base + mi * 16 + reg;
        const float v = acc[mi][ni][reg] + bv;
        const size_t o = (size_t)r * N + c;
        if (o0f) ((float*)out0)[out0_eoff + o] = v;
        else     ((bf16*)out0)[out0_eoff + o] = (bf16)v;
        if (out1) out1[o] = (bf16)(v > 0.f ? v : 0.f);
      }
  }
}

// ================= fallback generic GEMM (R1, proven) =================
#define BM 64
#define BN 64
#define BK 32
#define LDSP (BK + 8)

__global__ __launch_bounds__(256) void gemm_k(
    const void* __restrict__ A, const void* __restrict__ Bm,
    const void* __restrict__ bias,
    void* __restrict__ out0, unsigned long long out0_eoff, int o0_dt,
    bf16* __restrict__ out1,
    const int* __restrict__ dflag,
    unsigned long long b_eoff, unsigned long long bias_eoff,
    int M, int N, int K, int remapP, int remapQ, int a_dt)
{
  __shared__ bf16 As[BM][LDSP];
  __shared__ bf16 Bs[BN][LDSP];

  const int inf32 = *dflag;
  const bool af32 = res_f32(a_dt, inf32);
  const bool bf32 = (inf32 != 0);
  const bool o0f  = res_f32(o0_dt, inf32);

  const int tid = threadIdx.x;
  const int bm = blockIdx.x * BM;
  const int bn = blockIdx.y * BN;

  const int a_r = tid >> 2;
  const int a_k = (tid & 3) * 8;
  int a_row = bm + a_r;
  const bool a_ok = a_row < M;
  if (remapP) a_row = (a_row % remapP) * remapQ + (a_row / remapP);
  const size_t a_off = (size_t)a_row * (size_t)K;

  const int b_k = tid >> 3;
  const int b_ng = bn + (tid & 7) * 8;
  const int b_nl = (tid & 7) * 8;
  const bool n_vec = ((N & 7) == 0) && (b_ng + 8 <= N);

  const int wave = tid >> 6;
  const int lane = tid & 63;
  const int wm = (wave >> 1) * 32;
  const int wn = (wave & 1) * 32;
  const int lm = lane & 15;
  const int q  = lane >> 4;

  floatx4 acc00 = {0.f,0.f,0.f,0.f}, acc01 = {0.f,0.f,0.f,0.f};
  floatx4 acc10 = {0.f,0.f,0.f,0.f}, acc11 = {0.f,0.f,0.f,0.f};

  for (int k0 = 0; k0 < K; k0 += BK) {
    {
      union { bf16x8 v; bf16 e[8]; } av;
      const int kg = k0 + a_k;
      if (af32) {
        const float* Af = (const float*)A;
        if (a_ok && (kg + 8 <= K)) {
          floatx4 f0 = *(const floatx4*)(Af + a_off + kg);
          floatx4 f1 = *(const floatx4*)(Af + a_off + kg + 4);
          #pragma unroll
          for (int e = 0; e < 4; e++) { av.e[e] = (bf16)f0[e]; av.e[4 + e] = (bf16)f1[e]; }
        } else {
          #pragma unroll
          for (int e = 0; e < 8; e++) {
            const int kk = kg + e;
            av.e[e] = (a_ok && kk < K) ? (bf16)Af[a_off + kk] : (bf16)0.f;
          }
        }
      } else {
        const bf16* Ab = (const bf16*)A;
        if (a_ok && (kg + 8 <= K)) {
          av.v = *(const bf16x8*)(Ab + a_off + kg);
        } else {
          #pragma unroll
          for (int e = 0; e < 8; e++) {
            const int kk = kg + e;
            av.e[e] = (a_ok && kk < K) ? Ab[a_off + kk] : (bf16)0.f;
          }
        }
      }
      *(bf16x8*)&As[a_r][a_k] = av.v;
    }
    {
      union { bf16x8 v; bf16 e[8]; } bv;
      const int kg = k0 + b_k;
      if (bf32) {
        const float* Bf = (const float*)Bm + b_eoff;
        if ((kg < K) && n_vec) {
          floatx4 f0 = *(const floatx4*)(Bf + (size_t)kg * N + b_ng);
          floatx4 f1 = *(const floatx4*)(Bf + (size_t)kg * N + b_ng + 4);
          #pragma unroll
          for (int e = 0; e < 4; e++) { bv.e[e] = (bf16)f0[e]; bv.e[4 + e] = (bf16)f1[e]; }
        } else {
          #pragma unroll
          for (int e = 0; e < 8; e++) {
            const int nn = b_ng + e;
            bv.e[e] = (kg < K && nn < N) ? (bf16)Bf[(size_t)kg * N + nn] : (bf16)0.f;
          }
        }
      } else {
        const bf16* Bb = (const bf16*)Bm + b_eoff;
        if ((kg < K) && n_vec) {
          bv.v = *(const bf16x8*)(Bb + (size_t)kg * N + b_ng);
        } else {
          #pragma unroll
          for (int e = 0; e < 8; e++) {
            const int nn = b_ng + e;
            bv.e[e] = (kg < K && nn < N) ? Bb[(size_t)kg * N + nn] : (bf16)0.f;
          }
        }
      }
      #pragma unroll
      for (int e = 0; e < 8; e++) Bs[b_nl + e][b_k] = bv.e[e];
    }
    __syncthreads();

    const bf16x8 a0 = *(const bf16x8*)&As[wm + lm][q * 8];
    const bf16x8 a1 = *(const bf16x8*)&As[wm + 16 + lm][q * 8];
    const bf16x8 b0 = *(const bf16x8*)&Bs[wn + lm][q * 8];
    const bf16x8 b1 = *(const bf16x8*)&Bs[wn + 16 + lm][q * 8];
    acc00 = __builtin_amdgcn_mfma_f32_16x16x32_bf16(a0, b0, acc00, 0, 0, 0);
    acc01 = __builtin_amdgcn_mfma_f32_16x16x32_bf16(a0, b1, acc01, 0, 0, 0);
    acc10 = __builtin_amdgcn_mfma_f32_16x16x32_bf16(a1, b0, acc10, 0, 0, 0);
    acc11 = __builtin_amdgcn_mfma_f32_16x16x32_bf16(a1, b1, acc11, 0, 0, 0);
    __syncthreads();
  }

  floatx4 accs[2][2] = {{acc00, acc01}, {acc10, acc11}};
  const int r0 = bm + wm + q * 4;
  const int c0 = bn + wn + lm;
  #pragma unroll
  for (int i = 0; i < 2; i++) {
    #pragma unroll
    for (int j = 0; j < 2; j++) {
      const int c = c0 + j * 16;
      if (c >= N) continue;
      float bias_v = 0.f;
      if (bias) {
        bias_v = inf32 ? ((const float*)bias)[bias_eoff + c]
                       : (float)((const bf16*)bias)[bias_eoff + c];
      }
      #pragma unroll
      for (int reg = 0; reg < 4; reg++) {
        const int r = r0 + i * 16 + reg;
        if (r >= M) continue;
        const float v = accs[i][j][reg] + bias_v;
        const size_t o = (size_t)r * (size_t)N + c;
        if (o0f) ((float*)out0)[out0_eoff + o] = v;
        else     ((bf16*)out0)[out0_eoff + o] = (bf16)v;
        if (out1) out1[o] = (bf16)(v > 0.f ? v : 0.f);
      }
    }
  }
}

__device__ __forceinline__ float sigmoidf_(float x) { return 1.f / (1.f + __expf(-x)); }
__device__ __forceinline__ float tanhf_(float x)    { return 1.f - 2.f / (__expf(2.f * x) + 1.f); }

// vectorized scan: 2 (b,h) chains per thread, bf16 U. 256 blocks x 256 thr.
__global__ __launch_bounds__(256) void sru_scan2_k(
    const bf16* __restrict__ U,
    bf16* __restrict__ h,                      // [T,B,H] in-place
    const void* __restrict__ c0, unsigned long long c0_eoff,
    const void* __restrict__ bvec, unsigned long long bvec_eoff,
    const int* __restrict__ dflag,
    void* __restrict__ cout, unsigned long long cout_eoff)
{
  const int inf32 = *dflag;
  const int i2 = (blockIdx.x * 256 + threadIdx.x) * 2;  // base of 2 elems
  const int hh = i2 & (HDIM - 1);
  const int b = i2 >> 10;
  float bf_[2], br_[2], c[2];
  #pragma unroll
  for (int e = 0; e < 2; e++) {
    bf_[e] = inf32 ? ((const float*)bvec)[bvec_eoff + hh + e]
                   : (float)((const bf16*)bvec)[bvec_eoff + hh + e];
    br_[e] = inf32 ? ((const float*)bvec)[bvec_eoff + HDIM + hh + e]
                   : (float)((const bf16*)bvec)[bvec_eoff + HDIM + hh + e];
    c[e] = inf32 ? ((const float*)c0)[c0_eoff + i2 + e]
                 : (float)((const bf16*)c0)[c0_eoff + i2 + e];
  }
  #pragma unroll 4
  for (int t = 0; t < TT; t++) {
    const size_t off = (size_t)(t * BB + b) * (size_t)(3 * HDIM);
    const bf16x2 xt2 = *(const bf16x2*)(U + off + hh);
    const bf16x2 fp2 = *(const bf16x2*)(U + off + HDIM + hh);
    const bf16x2 rp2 = *(const bf16x2*)(U + off + 2 * HDIM + hh);
    const size_t hi = (size_t)t * (BB * HDIM) + i2;
    const bf16x2 hin2 = *(const bf16x2*)(h + hi);
    bf16x2 ho;
    #pragma unroll
    for (int e = 0; e < 2; e++) {
      const float fg = sigmoidf_((float)fp2[e] + bf_[e]);
      const float rg = sigmoidf_((float)rp2[e] + br_[e]);
      c[e] = fg * c[e] + (1.f - fg) * (float)xt2[e];
      ho[e] = (bf16)(rg * tanhf_(c[e]) + (1.f - rg) * (float)hin2[e]);
    }
    *(bf16x2*)(h + hi) = ho;
  }
  if (inf32) {
    floatx2 co; co[0] = c[0]; co[1] = c[1];
    *(floatx2*)((float*)cout + cout_eoff + i2) = co;
  } else {
    bf16x2 co; co[0] = (bf16)c[0]; co[1] = (bf16)c[1];
    *(bf16x2*)((bf16*)cout + cout_eoff + i2) = co;
  }
}

// fallback scan (scalar, fp32-or-bf16 U)
__global__ __launch_bounds__(256) void sru_scan_k(
    const void* __restrict__ U, int u_f32,
    bf16* __restrict__ h,
    const void* __restrict__ c0, unsigned long long c0_eoff,
    const void* __restrict__ bvec, unsigned long long bvec_eoff,
    const int* __restrict__ dflag,
    void* __restrict__ cout, unsigned long long cout_eoff)
{
  const int inf32 = *dflag;
  const int idx = blockIdx.x * 256 + threadIdx.x;
  const int hh = idx & (HDIM - 1);
  const int b = idx >> 10;
  const float bf_ = inf32 ? ((const float*)bvec)[bvec_eoff + hh]
                          : (float)((const bf16*)bvec)[bvec_eoff + hh];
  const float br_ = inf32 ? ((const float*)bvec)[bvec_eoff + HDIM + hh]
                          : (float)((const bf16*)bvec)[bvec_eoff + HDIM + hh];
  float c = inf32 ? ((const float*)c0)[c0_eoff + idx]
                  : (float)((const bf16*)c0)[c0_eoff + idx];
  const float* Uf = (const float*)U;
  const bf16*  Ub = (const bf16*)U;
  #pragma unroll 4
  for (int t = 0; t < TT; t++) {
    const size_t off = (size_t)(t * BB + b) * (size_t)(3 * HDIM);
    const float xt = u_f32 ? Uf[off + hh] : (float)Ub[off + hh];
    const float fp = u_f32 ? Uf[off + HDIM + hh] : (float)Ub[off + HDIM + hh];
    const float rp = u_f32 ? Uf[off + 2 * HDIM + hh] : (float)Ub[off + 2 * HDIM + hh];
    const float fg = sigmoidf_(fp + bf_);
    const float rg = sigmoidf_(rp + br_);
    c = fg * c + (1.f - fg) * xt;
    const size_t hi = (size_t)t * (BB * HDIM) + idx;
    const float xin = (float)h[hi];
    h[hi] = (bf16)(rg * tanhf_(c) + (1.f - rg) * xin);
  }
  if (inf32) ((float*)cout)[cout_eoff + idx] = c;
  else       ((bf16*)cout)[cout_eoff + idx] = (bf16)c;
}

extern "C" void kernel_launch(void* const* d_in, const int* in_sizes, int n_in,
                              void* d_out, int out_size, void* d_ws, size_t ws_size,
                              hipStream_t stream) {
  const void* x       = d_in[0];
  const void* hidden0 = d_in[1];
  const void* W1      = d_in[2];
  const void* b1      = d_in[3];
  const void* sru_W   = d_in[4];
  const void* sru_b   = d_in[5];
  const void* W3      = d_in[6];
  const void* b3      = d_in[7];
  const void* W4      = d_in[8];
  const void* b4      = d_in[9];

  const unsigned long long eo_fx  = (unsigned long long)MROWS * OUTN;
  const unsigned long long eo_hid = eo_fx + (unsigned long long)MROWS * HDIM;

  const size_t z_flag = 256;
  const size_t z_hA   = (size_t)MROWS * HDIM * 2;
  const size_t z_U    = (size_t)MROWS * 3 * HDIM * 4;  // fp32-sized slab (fast path uses half, bf16)
  const size_t z_xc   = (size_t)MROWS * KPAD1 * 2;
  const size_t z_W1T  = (size_t)HDIM * KPAD1 * 2;
  const size_t z_sWT  = (size_t)LNUM * 3 * HDIM * HDIM * 2;
  const size_t z_W3T  = (size_t)HDIM * HDIM * 2;
  const size_t z_W4T  = (size_t)NPAD4 * HDIM * 2;
  const size_t FAST_NEED = z_flag + z_hA + z_U + z_xc + z_W1T + z_sWT + z_W3T + z_W4T;

  int* dflag = (int*)d_ws;
  char* p = (char*)d_ws + z_flag;
  bf16*  hA    = (bf16*)p;            p += z_hA;
  char*  Ubase = p;                   p += z_U;
  bf16*  xc    = (bf16*)p;            p += z_xc;
  bf16*  W1T   = (bf16*)p;            p += z_W1T;
  bf16*  sWT   = (bf16*)p;            p += z_sWT;
  bf16*  W3T   = (bf16*)p;            p += z_W3T;
  bf16*  W4T   = (bf16*)p;
  bf16*  Ub = (bf16*)Ubase;   // fast path: U as bf16
  bf16*  y  = (bf16*)Ubase;   // aliases U; live only after all U uses done

  dim3 blk(256);
  detect_k<<<1, 64, 0, stream>>>((const unsigned int*)W1, dflag);

  if (ws_size >= FAST_NEED) {
    convx_k<<<dim3((MROWS * KPAD1 + 255) / 256), blk, 0, stream>>>(x, dflag, xc);
    transp_k<<<dim3(KPAD1 / 32, HDIM / 32, 1), blk, 0, stream>>>(
        W1, dflag, W1T, D_IN, HDIM, KPAD1, HDIM, 0ull, 0ull);
    ftransp_k<<<dim3(HDIM / 64, 3 * HDIM / 64, LNUM), blk, 0, stream>>>(
        sru_W, dflag, sWT, HDIM, 3 * HDIM, 3 * HDIM,
        (unsigned long long)HDIM * 3 * HDIM, (unsigned long long)3 * HDIM * HDIM);
    ftransp_k<<<dim3(HDIM / 64, HDIM / 64, 1), blk, 0, stream>>>(
        W3, dflag, W3T, HDIM, HDIM, HDIM, 0ull, 0ull);
    ftransp_k<<<dim3(HDIM / 64, NPAD4 / 64, 1), blk, 0, stream>>>(
        W4, dflag, W4T, HDIM, OUTN, NPAD4, 0ull, 0ull);

    gemm_f<<<dim3(MROWS / 128, HDIM / 128), blk, 0, stream>>>(
        xc, W1T, b1, 0ull, dflag, hA, 0ull, 0, nullptr, HDIM, KPAD1, 0, 0);

    for (int l = 0; l < LNUM; l++) {
      gemm_f<<<dim3(MROWS / 128, 3 * HDIM / 128), blk, 0, stream>>>(
          hA, sWT + (size_t)l * 3 * HDIM * HDIM, nullptr, 0ull, dflag,
          Ub, 0ull, 0, nullptr, 3 * HDIM, HDIM, 0, 0);
      sru_scan2_k<<<dim3((BB * HDIM) / 512), blk, 0, stream>>>(
          Ub, hA, hidden0, (unsigned long long)l * BB * HDIM,
          sru_b, (unsigned long long)l * 2 * HDIM,
          dflag, d_out, eo_hid + (unsigned long long)l * BB * HDIM);
    }

    gemm_f<<<dim3(MROWS / 128, HDIM / 128), blk, 0, stream>>>(
        hA, W3T, b3, 0ull, dflag, d_out, eo_fx, 2, y, HDIM, HDIM, TT, BB);

    gemm_f<<<dim3(MROWS / 128, NPAD4 / 128), blk, 0, stream>>>(
        y, W4T, b4, 0ull, dflag, d_out, 0ull, 2, nullptr, OUTN, HDIM, 0, 0);
  } else {
    const size_t need_f32U = z_flag + z_hA + z_U;
    const int u_f32 = (ws_size >= need_f32U) ? 1 : 0;
    void* U = (void*)Ubase;

    gemm_k<<<dim3(MROWS / BM, HDIM / BN), blk, 0, stream>>>(
        x, W1, b1, hA, 0ull, 0, nullptr, dflag, 0ull, 0ull,
        MROWS, HDIM, D_IN, BB, TT, 2);

    for (int l = 0; l < LNUM; l++) {
      gemm_k<<<dim3(MROWS / BM, (3 * HDIM) / BN), blk, 0, stream>>>(
          hA, sru_W, nullptr, U, 0ull, (u_f32 ? 1 : 0), nullptr, dflag,
          (unsigned long long)l * HDIM * 3 * HDIM, 0ull,
          MROWS, 3 * HDIM, HDIM, 0, 0, 0);
      sru_scan_k<<<dim3((BB * HDIM) / 256), blk, 0, stream>>>(
          U, u_f32, hA, hidden0, (unsigned long long)l * BB * HDIM,
          sru_b, (unsigned long long)l * 2 * HDIM,
          dflag, d_out, eo_hid + (unsigned long long)l * BB * HDIM);
    }

    gemm_k<<<dim3(MROWS / BM, HDIM / BN), blk, 0, stream>>>(
        hA, W3, b3, d_out, eo_fx, 2, y, dflag, 0ull, 0ull,
        MROWS, HDIM, HDIM, TT, BB, 0);

    gemm_k<<<dim3(MROWS / BM, (OUTN + BN - 1) / BN), blk, 0, stream>>>(
        y, W4, b4, d_out, 0ull, 2, nullptr, dflag, 0ull, 0ull,
        MROWS, OUTN, HDIM, 0, 0, 0);
  }
}

// Round 6
// 798.216 us; speedup vs baseline: 2.0485x; 1.0600x over previous
//
#include <hip/hip_runtime.h>

// ---- problem constants ----
#define D_IN  200
#define KPAD1 224   // D_IN padded to multiple of 32
#define HDIM  1024
#define OUTN  1095
#define NPAD4 1152  // OUTN padded to multiple of 128
#define LNUM  12
#define BB    128
#define TT    20
#define MROWS (BB * TT)  // 2560

typedef __bf16 bf16;
typedef __attribute__((ext_vector_type(2))) __bf16 bf16x2;
typedef __attribute__((ext_vector_type(8))) __bf16 bf16x8;
typedef __attribute__((ext_vector_type(2))) float floatx2;
typedef __attribute__((ext_vector_type(4))) float floatx4;

// dtype codes: 0 = bf16, 1 = fp32, 2 = follow detected input dtype
__device__ __forceinline__ bool res_f32(int dt, int inf32) {
  return dt == 1 || (dt == 2 && inf32 != 0);
}

// Detect input dtype from W1's raw words. flag=1 => fp32 inputs.
__global__ __launch_bounds__(64) void detect_k(const unsigned int* __restrict__ w,
                                               int* __restrict__ flag) {
  int cnt = 0;
  for (int i = threadIdx.x; i < 1024; i += 64) {
    unsigned int ex = (w[i] >> 7) & 0xFFu;
    if (ex >= 104u && ex <= 131u) cnt++;
  }
  #pragma unroll
  for (int off = 32; off; off >>= 1) cnt += __shfl_down(cnt, off);
  if (threadIdx.x == 0) *flag = (cnt > 512) ? 0 : 1;
}

// ---- fast transpose: out[n][K] = in[k][n], K%64==0, Npad%64==0, batched ----
__global__ __launch_bounds__(256) void ftransp_k(
    const void* __restrict__ in, const int* __restrict__ dflag,
    bf16* __restrict__ out, int K, int N, int Npad,
    unsigned long long in_bs, unsigned long long out_bs)
{
  __shared__ float tile[64][69];
  const int inf32 = *dflag;
  const int t = threadIdx.x;
  const int kt = blockIdx.x * 64, nt = blockIdx.y * 64;
  const float* inf = (const float*)in + (size_t)blockIdx.z * in_bs;
  const bf16*  inb = (const bf16*)in + (size_t)blockIdx.z * in_bs;

  const int lk = t >> 2;               // 0..63
  const size_t rbase = (size_t)(kt + lk) * N;
  #pragma unroll
  for (int j = 0; j < 4; j++) {
    const int ln = ((t & 3) + 4 * j) * 4;   // 0..60 step 4
    const int gn = nt + ln;
    floatx4 v = {0.f, 0.f, 0.f, 0.f};
    if (inf32) {
      if (gn + 4 <= N) {
        v = *(const floatx4*)(inf + rbase + gn);
      } else {
        #pragma unroll
        for (int e = 0; e < 4; e++) if (gn + e < N) v[e] = inf[rbase + gn + e];
      }
    } else {
      #pragma unroll
      for (int e = 0; e < 4; e++) if (gn + e < N) v[e] = (float)inb[rbase + gn + e];
    }
    #pragma unroll
    for (int e = 0; e < 4; e++) tile[lk][ln + e] = v[e];
  }
  __syncthreads();

  const int n  = t >> 2;               // 0..63
  const int kc = (t & 3) * 16;         // 0..48
  union { bf16x8 v[2]; bf16 e[16]; } o;
  #pragma unroll
  for (int i = 0; i < 16; i++) o.e[i] = (bf16)tile[kc + i][n];
  bf16* op = out + (size_t)blockIdx.z * out_bs + (size_t)(nt + n) * K + kt + kc;
  *(bf16x8*)op = o.v[0];
  *(bf16x8*)(op + 8) = o.v[1];
}

// small generic transpose (kept for W1: K=200 not %64)
__global__ __launch_bounds__(256) void transp_k(
    const void* __restrict__ in, const int* __restrict__ dflag,
    bf16* __restrict__ out, int K, int N, int Kpad, int Npad,
    unsigned long long in_bs, unsigned long long out_bs)
{
  __shared__ float tile[32][33];
  const int inf32 = *dflag;
  const int tx = threadIdx.x & 31, ty = threadIdx.x >> 5;
  const int kt = blockIdx.x * 32, nt = blockIdx.y * 32;
  const float* inf = (const float*)in + (size_t)blockIdx.z * in_bs;
  const bf16*  inb = (const bf16*)in + (size_t)blockIdx.z * in_bs;
  #pragma unroll
  for (int j = 0; j < 4; j++) {
    const int k = kt + ty + j * 8, n = nt + tx;
    float v = 0.f;
    if (k < K && n < N)
      v = inf32 ? inf[(size_t)k * N + n] : (float)inb[(size_t)k * N + n];
    tile[ty + j * 8][tx] = v;
  }
  __syncthreads();
  bf16* o = out + (size_t)blockIdx.z * out_bs;
  #pragma unroll
  for (int j = 0; j < 4; j++) {
    const int n = nt + ty + j * 8, k = kt + tx;
    if (n < Npad && k < Kpad) o[(size_t)n * Kpad + k] = (bf16)tile[tx][ty + j * 8];
  }
}

// xc[t*B+b][0..KPAD1) <- x[b][t][0..D_IN) (zero-padded), bf16
__global__ __launch_bounds__(256) void convx_k(
    const void* __restrict__ x, const int* __restrict__ dflag, bf16* __restrict__ xc)
{
  const int inf32 = *dflag;
  const int idx = blockIdx.x * 256 + threadIdx.x;
  if (idx >= MROWS * KPAD1) return;
  const int row = idx / KPAD1;
  const int d = idx - row * KPAD1;
  const int t = row / BB, b = row - t * BB;
  float v = 0.f;
  if (d < D_IN) {
    const size_t src = ((size_t)b * TT + t) * D_IN + d;
    v = inf32 ? ((const float*)x)[src] : (float)((const bf16*)x)[src];
  }
  xc[idx] = (bf16)v;
}

// ---- fast GEMM: 128x128 tile, BK=64 (two 32-wide LDS buffers, 32 MFMA per barrier) ----
// A [M,Ks] bf16 k-contig (rows optionally remapped), Bt [Npad,Ks] bf16 k-contig.
// M % 128 == 0, Ks % 32 == 0, Npad % 128 == 0 (zero rows beyond N).
__global__ __launch_bounds__(256) void gemm_f(
    const bf16* __restrict__ A, const bf16* __restrict__ Bt,
    const void* __restrict__ bias, unsigned long long bias_eoff,
    const int* __restrict__ dflag,
    void* __restrict__ out0, unsigned long long out0_eoff, int o0_dt,
    bf16* __restrict__ out1,
    int N, int Ks, int remapP, int remapQ)
{
  __shared__ bf16 As[2][128 * 32];
  __shared__ bf16 Bs[2][128 * 32];
  const int inf32 = *dflag;
  const bool o0f = res_f32(o0_dt, inf32);

  const int tid = threadIdx.x;
  const int wave = tid >> 6, lane = tid & 63;
  const int wr = wave >> 1, wc = wave & 1;
  const int lm = lane & 15, q = lane >> 4;
  const int l4r = lane >> 2, l4k = (lane & 3) * 8;

  const int bm = blockIdx.x * 128, bn = blockIdx.y * 128;

  int ar0 = bm + wave * 32 + l4r;
  int ar1 = ar0 + 16;
  if (remapP) {
    ar0 = (ar0 % remapP) * remapQ + ar0 / remapP;
    ar1 = (ar1 % remapP) * remapQ + ar1 / remapP;
  }
  const bf16* gA0 = A + (size_t)ar0 * Ks + l4k;
  const bf16* gA1 = A + (size_t)ar1 * Ks + l4k;
  const bf16* gB0 = Bt + (size_t)(bn + wave * 32 + l4r) * Ks + l4k;
  const bf16* gB1 = gB0 + (size_t)16 * Ks;

  auto* As30 = (__attribute__((address_space(3))) char*)As[0];
  auto* As31 = (__attribute__((address_space(3))) char*)As[1];
  auto* Bs30 = (__attribute__((address_space(3))) char*)Bs[0];
  auto* Bs31 = (__attribute__((address_space(3))) char*)Bs[1];
  const int lds0 = (wave * 32) * 64;
  const int lds1 = lds0 + 16 * 64;

  floatx4 acc[4][4];
  #pragma unroll
  for (int i = 0; i < 4; i++)
    #pragma unroll
    for (int j = 0; j < 4; j++) acc[i][j] = (floatx4){0.f, 0.f, 0.f, 0.f};

  const int k64 = Ks & ~63;  // full 64-chunks
  for (int k0 = 0; k0 < k64; k0 += 64) {
    __builtin_amdgcn_global_load_lds((const __attribute__((address_space(1))) void*)gA0,
                                     (__attribute__((address_space(3))) void*)(As30 + lds0), 16, 0, 0);
    __builtin_amdgcn_global_load_lds((const __attribute__((address_space(1))) void*)gA1,
                                     (__attribute__((address_space(3))) void*)(As30 + lds1), 16, 0, 0);
    __builtin_amdgcn_global_load_lds((const __attribute__((address_space(1))) void*)gB0,
                                     (__attribute__((address_space(3))) void*)(Bs30 + lds0), 16, 0, 0);
    __builtin_amdgcn_global_load_lds((const __attribute__((address_space(1))) void*)gB1,
                                     (__attribute__((address_space(3))) void*)(Bs30 + lds1), 16, 0, 0);
    __builtin_amdgcn_global_load_lds((const __attribute__((address_space(1))) void*)(gA0 + 32),
                                     (__attribute__((address_space(3))) void*)(As31 + lds0), 16, 0, 0);
    __builtin_amdgcn_global_load_lds((const __attribute__((address_space(1))) void*)(gA1 + 32),
                                     (__attribute__((address_space(3))) void*)(As31 + lds1), 16, 0, 0);
    __builtin_amdgcn_global_load_lds((const __attribute__((address_space(1))) void*)(gB0 + 32),
                                     (__attribute__((address_space(3))) void*)(Bs31 + lds0), 16, 0, 0);
    __builtin_amdgcn_global_load_lds((const __attribute__((address_space(1))) void*)(gB1 + 32),
                                     (__attribute__((address_space(3))) void*)(Bs31 + lds1), 16, 0, 0);
    gA0 += 64; gA1 += 64; gB0 += 64; gB1 += 64;
    __syncthreads();

    #pragma unroll
    for (int s = 0; s < 2; s++) {
      bf16x8 af[4], bfr[4];
      #pragma unroll
      for (int mi = 0; mi < 4; mi++)
        af[mi] = *(const bf16x8*)&As[s][(wr * 64 + mi * 16 + lm) * 32 + q * 8];
      #pragma unroll
      for (int ni = 0; ni < 4; ni++)
        bfr[ni] = *(const bf16x8*)&Bs[s][(wc * 64 + ni * 16 + lm) * 32 + q * 8];
      #pragma unroll
      for (int mi = 0; mi < 4; mi++)
        #pragma unroll
        for (int ni = 0; ni < 4; ni++)
          acc[mi][ni] = __builtin_amdgcn_mfma_f32_16x16x32_bf16(af[mi], bfr[ni], acc[mi][ni], 0, 0, 0);
    }
    __syncthreads();
  }

  if (k64 < Ks) {  // 32-tail (e.g. Ks=224)
    __builtin_amdgcn_global_load_lds((const __attribute__((address_space(1))) void*)gA0,
                                     (__attribute__((address_space(3))) void*)(As30 + lds0), 16, 0, 0);
    __builtin_amdgcn_global_load_lds((const __attribute__((address_space(1))) void*)gA1,
                                     (__attribute__((address_space(3))) void*)(As30 + lds1), 16, 0, 0);
    __builtin_amdgcn_global_load_lds((const __attribute__((address_space(1))) void*)gB0,
                                     (__attribute__((address_space(3))) void*)(Bs30 + lds0), 16, 0, 0);
    __builtin_amdgcn_global_load_lds((const __attribute__((address_space(1))) void*)gB1,
                                     (__attribute__((address_space(3))) void*)(Bs30 + lds1), 16, 0, 0);
    __syncthreads();
    bf16x8 af[4], bfr[4];
    #pragma unroll
    for (int mi = 0; mi < 4; mi++)
      af[mi] = *(const bf16x8*)&As[0][(wr * 64 + mi * 16 + lm) * 32 + q * 8];
    #pragma unroll
    for (int ni = 0; ni < 4; ni++)
      bfr[ni] = *(const bf16x8*)&Bs[0][(wc * 64 + ni * 16 + lm) * 32 + q * 8];
    #pragma unroll
    for (int mi = 0; mi < 4; mi++)
      #pragma unroll
      for (int ni = 0; ni < 4; ni++)
        acc[mi][ni] = __builtin_amdgcn_mfma_f32_16x16x32_bf16(af[mi], bfr[ni], acc[mi][ni], 0, 0, 0);
    __syncthreads();
  }

  const int row_base = bm + wr * 64 + q * 4;
  const int col_base = bn + wc * 64 + lm;
  #pragma unroll
  for (int ni = 0; ni < 4; ni++) {
    const int c = col_base + ni * 16;
    if (c >= N) continue;
    float bv = 0.f;
    if (bias)
      bv = inf32 ? ((const float*)bias)[bias_eoff + c]
                 : (float)((const bf16*)bias)[bias_eoff + c];
    #pragma unroll
    for (int mi = 0; mi < 4; mi++)
      #pragma unroll
      for (int reg = 0; reg < 4; reg++) {
        const int r = row_base + mi * 16 + reg;
        const float v = acc[mi][ni][reg] + bv;
        const size_t o = (size_t)r * N + c;
        if (o0f) ((float*)out0)[out0_eoff + o] = v;
        else     ((bf16*)out0)[out0_eoff + o] = (bf16)v;
        if (out1) out1[o] = (bf16)(v > 0.f ? v : 0.f);
      }
  }
}

// ================= fallback generic GEMM (R1, proven) =================
#define BM 64
#define BN 64
#define BK 32
#define LDSP (BK + 8)

__global__ __launch_bounds__(256) void gemm_k(
    const void* __restrict__ A, const void* __restrict__ Bm,
    const void* __restrict__ bias,
    void* __restrict__ out0, unsigned long long out0_eoff, int o0_dt,
    bf16* __restrict__ out1,
    const int* __restrict__ dflag,
    unsigned long long b_eoff, unsigned long long bias_eoff,
    int M, int N, int K, int remapP, int remapQ, int a_dt)
{
  __shared__ bf16 As[BM][LDSP];
  __shared__ bf16 Bs[BN][LDSP];

  const int inf32 = *dflag;
  const bool af32 = res_f32(a_dt, inf32);
  const bool bf32 = (inf32 != 0);
  const bool o0f  = res_f32(o0_dt, inf32);

  const int tid = threadIdx.x;
  const int bm = blockIdx.x * BM;
  const int bn = blockIdx.y * BN;

  const int a_r = tid >> 2;
  const int a_k = (tid & 3) * 8;
  int a_row = bm + a_r;
  const bool a_ok = a_row < M;
  if (remapP) a_row = (a_row % remapP) * remapQ + (a_row / remapP);
  const size_t a_off = (size_t)a_row * (size_t)K;

  const int b_k = tid >> 3;
  const int b_ng = bn + (tid & 7) * 8;
  const int b_nl = (tid & 7) * 8;
  const bool n_vec = ((N & 7) == 0) && (b_ng + 8 <= N);

  const int wave = tid >> 6;
  const int lane = tid & 63;
  const int wm = (wave >> 1) * 32;
  const int wn = (wave & 1) * 32;
  const int lm = lane & 15;
  const int q  = lane >> 4;

  floatx4 acc00 = {0.f,0.f,0.f,0.f}, acc01 = {0.f,0.f,0.f,0.f};
  floatx4 acc10 = {0.f,0.f,0.f,0.f}, acc11 = {0.f,0.f,0.f,0.f};

  for (int k0 = 0; k0 < K; k0 += BK) {
    {
      union { bf16x8 v; bf16 e[8]; } av;
      const int kg = k0 + a_k;
      if (af32) {
        const float* Af = (const float*)A;
        if (a_ok && (kg + 8 <= K)) {
          floatx4 f0 = *(const floatx4*)(Af + a_off + kg);
          floatx4 f1 = *(const floatx4*)(Af + a_off + kg + 4);
          #pragma unroll
          for (int e = 0; e < 4; e++) { av.e[e] = (bf16)f0[e]; av.e[4 + e] = (bf16)f1[e]; }
        } else {
          #pragma unroll
          for (int e = 0; e < 8; e++) {
            const int kk = kg + e;
            av.e[e] = (a_ok && kk < K) ? (bf16)Af[a_off + kk] : (bf16)0.f;
          }
        }
      } else {
        const bf16* Ab = (const bf16*)A;
        if (a_ok && (kg + 8 <= K)) {
          av.v = *(const bf16x8*)(Ab + a_off + kg);
        } else {
          #pragma unroll
          for (int e = 0; e < 8; e++) {
            const int kk = kg + e;
            av.e[e] = (a_ok && kk < K) ? Ab[a_off + kk] : (bf16)0.f;
          }
        }
      }
      *(bf16x8*)&As[a_r][a_k] = av.v;
    }
    {
      union { bf16x8 v; bf16 e[8]; } bv;
      const int kg = k0 + b_k;
      if (bf32) {
        const float* Bf = (const float*)Bm + b_eoff;
        if ((kg < K) && n_vec) {
          floatx4 f0 = *(const floatx4*)(Bf + (size_t)kg * N + b_ng);
          floatx4 f1 = *(const floatx4*)(Bf + (size_t)kg * N + b_ng + 4);
          #pragma unroll
          for (int e = 0; e < 4; e++) { bv.e[e] = (bf16)f0[e]; bv.e[4 + e] = (bf16)f1[e]; }
        } else {
          #pragma unroll
          for (int e = 0; e < 8; e++) {
            const int nn = b_ng + e;
            bv.e[e] = (kg < K && nn < N) ? (bf16)Bf[(size_t)kg * N + nn] : (bf16)0.f;
          }
        }
      } else {
        const bf16* Bb = (const bf16*)Bm + b_eoff;
        if ((kg < K) && n_vec) {
          bv.v = *(const bf16x8*)(Bb + (size_t)kg * N + b_ng);
        } else {
          #pragma unroll
          for (int e = 0; e < 8; e++) {
            const int nn = b_ng + e;
            bv.e[e] = (kg < K && nn < N) ? Bb[(size_t)kg * N + nn] : (bf16)0.f;
          }
        }
      }
      #pragma unroll
      for (int e = 0; e < 8; e++) Bs[b_nl + e][b_k] = bv.e[e];
    }
    __syncthreads();

    const bf16x8 a0 = *(const bf16x8*)&As[wm + lm][q * 8];
    const bf16x8 a1 = *(const bf16x8*)&As[wm + 16 + lm][q * 8];
    const bf16x8 b0 = *(const bf16x8*)&Bs[wn + lm][q * 8];
    const bf16x8 b1 = *(const bf16x8*)&Bs[wn + 16 + lm][q * 8];
    acc00 = __builtin_amdgcn_mfma_f32_16x16x32_bf16(a0, b0, acc00, 0, 0, 0);
    acc01 = __builtin_amdgcn_mfma_f32_16x16x32_bf16(a0, b1, acc01, 0, 0, 0);
    acc10 = __builtin_amdgcn_mfma_f32_16x16x32_bf16(a1, b0, acc10, 0, 0, 0);
    acc11 = __builtin_amdgcn_mfma_f32_16x16x32_bf16(a1, b1, acc11, 0, 0, 0);
    __syncthreads();
  }

  floatx4 accs[2][2] = {{acc00, acc01}, {acc10, acc11}};
  const int r0 = bm + wm + q * 4;
  const int c0 = bn + wn + lm;
  #pragma unroll
  for (int i = 0; i < 2; i++) {
    #pragma unroll
    for (int j = 0; j < 2; j++) {
      const int c = c0 + j * 16;
      if (c >= N) continue;
      float bias_v = 0.f;
      if (bias) {
        bias_v = inf32 ? ((const float*)bias)[bias_eoff + c]
                       : (float)((const bf16*)bias)[bias_eoff + c];
      }
      #pragma unroll
      for (int reg = 0; reg < 4; reg++) {
        const int r = r0 + i * 16 + reg;
        if (r >= M) continue;
        const float v = accs[i][j][reg] + bias_v;
        const size_t o = (size_t)r * (size_t)N + c;
        if (o0f) ((float*)out0)[out0_eoff + o] = v;
        else     ((bf16*)out0)[out0_eoff + o] = (bf16)v;
        if (out1) out1[o] = (bf16)(v > 0.f ? v : 0.f);
      }
    }
  }
}

__device__ __forceinline__ float sigmoidf_(float x) { return 1.f / (1.f + __expf(-x)); }
__device__ __forceinline__ float tanhf_(float x)    { return 1.f - 2.f / (__expf(2.f * x) + 1.f); }

// vectorized scan: 2 (b,h) chains per thread, bf16 U. 256 blocks x 256 thr.
__global__ __launch_bounds__(256) void sru_scan2_k(
    const bf16* __restrict__ U,
    bf16* __restrict__ h,                      // [T,B,H] in-place
    const void* __restrict__ c0, unsigned long long c0_eoff,
    const void* __restrict__ bvec, unsigned long long bvec_eoff,
    const int* __restrict__ dflag,
    void* __restrict__ cout, unsigned long long cout_eoff)
{
  const int inf32 = *dflag;
  const int i2 = (blockIdx.x * 256 + threadIdx.x) * 2;  // base of 2 elems
  const int hh = i2 & (HDIM - 1);
  const int b = i2 >> 10;
  float bf_[2], br_[2], c[2];
  #pragma unroll
  for (int e = 0; e < 2; e++) {
    bf_[e] = inf32 ? ((const float*)bvec)[bvec_eoff + hh + e]
                   : (float)((const bf16*)bvec)[bvec_eoff + hh + e];
    br_[e] = inf32 ? ((const float*)bvec)[bvec_eoff + HDIM + hh + e]
                   : (float)((const bf16*)bvec)[bvec_eoff + HDIM + hh + e];
    c[e] = inf32 ? ((const float*)c0)[c0_eoff + i2 + e]
                 : (float)((const bf16*)c0)[c0_eoff + i2 + e];
  }
  #pragma unroll 4
  for (int t = 0; t < TT; t++) {
    const size_t off = (size_t)(t * BB + b) * (size_t)(3 * HDIM);
    const bf16x2 xt2 = *(const bf16x2*)(U + off + hh);
    const bf16x2 fp2 = *(const bf16x2*)(U + off + HDIM + hh);
    const bf16x2 rp2 = *(const bf16x2*)(U + off + 2 * HDIM + hh);
    const size_t hi = (size_t)t * (BB * HDIM) + i2;
    const bf16x2 hin2 = *(const bf16x2*)(h + hi);
    bf16x2 ho;
    #pragma unroll
    for (int e = 0; e < 2; e++) {
      const float fg = sigmoidf_((float)fp2[e] + bf_[e]);
      const float rg = sigmoidf_((float)rp2[e] + br_[e]);
      c[e] = fg * c[e] + (1.f - fg) * (float)xt2[e];
      ho[e] = (bf16)(rg * tanhf_(c[e]) + (1.f - rg) * (float)hin2[e]);
    }
    *(bf16x2*)(h + hi) = ho;
  }
  if (inf32) {
    floatx2 co; co[0] = c[0]; co[1] = c[1];
    *(floatx2*)((float*)cout + cout_eoff + i2) = co;
  } else {
    bf16x2 co; co[0] = (bf16)c[0]; co[1] = (bf16)c[1];
    *(bf16x2*)((bf16*)cout + cout_eoff + i2) = co;
  }
}

// fallback scan (scalar, fp32-or-bf16 U)
__global__ __launch_bounds__(256) void sru_scan_k(
    const void* __restrict__ U, int u_f32,
    bf16* __restrict__ h,
    const void* __restrict__ c0, unsigned long long c0_eoff,
    const void* __restrict__ bvec, unsigned long long bvec_eoff,
    const int* __restrict__ dflag,
    void* __restrict__ cout, unsigned long long cout_eoff)
{
  const int inf32 = *dflag;
  const int idx = blockIdx.x * 256 + threadIdx.x;
  const int hh = idx & (HDIM - 1);
  const int b = idx >> 10;
  const float bf_ = inf32 ? ((const float*)bvec)[bvec_eoff + hh]
                          : (float)((const bf16*)bvec)[bvec_eoff + hh];
  const float br_ = inf32 ? ((const float*)bvec)[bvec_eoff + HDIM + hh]
                          : (float)((const bf16*)bvec)[bvec_eoff + HDIM + hh];
  float c = inf32 ? ((const float*)c0)[c0_eoff + idx]
                  : (float)((const bf16*)c0)[c0_eoff + idx];
  const float* Uf = (const float*)U;
  const bf16*  Ub = (const bf16*)U;
  #pragma unroll 4
  for (int t = 0; t < TT; t++) {
    const size_t off = (size_t)(t * BB + b) * (size_t)(3 * HDIM);
    const float xt = u_f32 ? Uf[off + hh] : (float)Ub[off + hh];
    const float fp = u_f32 ? Uf[off + HDIM + hh] : (float)Ub[off + HDIM + hh];
    const float rp = u_f32 ? Uf[off + 2 * HDIM + hh] : (float)Ub[off + 2 * HDIM + hh];
    const float fg = sigmoidf_(fp + bf_);
    const float rg = sigmoidf_(rp + br_);
    c = fg * c + (1.f - fg) * xt;
    const size_t hi = (size_t)t * (BB * HDIM) + idx;
    const float xin = (float)h[hi];
    h[hi] = (bf16)(rg * tanhf_(c) + (1.f - rg) * xin);
  }
  if (inf32) ((float*)cout)[cout_eoff + idx] = c;
  else       ((bf16*)cout)[cout_eoff + idx] = (bf16)c;
}

extern "C" void kernel_launch(void* const* d_in, const int* in_sizes, int n_in,
                              void* d_out, int out_size, void* d_ws, size_t ws_size,
                              hipStream_t stream) {
  const void* x       = d_in[0];
  const void* hidden0 = d_in[1];
  const void* W1      = d_in[2];
  const void* b1      = d_in[3];
  const void* sru_W   = d_in[4];
  const void* sru_b   = d_in[5];
  const void* W3      = d_in[6];
  const void* b3      = d_in[7];
  const void* W4      = d_in[8];
  const void* b4      = d_in[9];

  const unsigned long long eo_fx  = (unsigned long long)MROWS * OUTN;
  const unsigned long long eo_hid = eo_fx + (unsigned long long)MROWS * HDIM;

  const size_t z_flag = 256;
  const size_t z_hA   = (size_t)MROWS * HDIM * 2;
  const size_t z_U    = (size_t)MROWS * 3 * HDIM * 4;  // fp32-sized slab (fast path uses half, bf16)
  const size_t z_xc   = (size_t)MROWS * KPAD1 * 2;
  const size_t z_W1T  = (size_t)HDIM * KPAD1 * 2;
  const size_t z_sWT  = (size_t)LNUM * 3 * HDIM * HDIM * 2;
  const size_t z_W3T  = (size_t)HDIM * HDIM * 2;
  const size_t z_W4T  = (size_t)NPAD4 * HDIM * 2;
  const size_t FAST_NEED = z_flag + z_hA + z_U + z_xc + z_W1T + z_sWT + z_W3T + z_W4T;

  int* dflag = (int*)d_ws;
  char* p = (char*)d_ws + z_flag;
  bf16*  hA    = (bf16*)p;            p += z_hA;
  char*  Ubase = p;                   p += z_U;
  bf16*  xc    = (bf16*)p;            p += z_xc;
  bf16*  W1T   = (bf16*)p;            p += z_W1T;
  bf16*  sWT   = (bf16*)p;            p += z_sWT;
  bf16*  W3T   = (bf16*)p;            p += z_W3T;
  bf16*  W4T   = (bf16*)p;
  bf16*  Ub = (bf16*)Ubase;   // fast path: U as bf16
  bf16*  y  = (bf16*)Ubase;   // aliases U; live only after all U uses done

  dim3 blk(256);
  detect_k<<<1, 64, 0, stream>>>((const unsigned int*)W1, dflag);

  if (ws_size >= FAST_NEED) {
    convx_k<<<dim3((MROWS * KPAD1 + 255) / 256), blk, 0, stream>>>(x, dflag, xc);
    transp_k<<<dim3(KPAD1 / 32, HDIM / 32, 1), blk, 0, stream>>>(
        W1, dflag, W1T, D_IN, HDIM, KPAD1, HDIM, 0ull, 0ull);
    ftransp_k<<<dim3(HDIM / 64, 3 * HDIM / 64, LNUM), blk, 0, stream>>>(
        sru_W, dflag, sWT, HDIM, 3 * HDIM, 3 * HDIM,
        (unsigned long long)HDIM * 3 * HDIM, (unsigned long long)3 * HDIM * HDIM);
    ftransp_k<<<dim3(HDIM / 64, HDIM / 64, 1), blk, 0, stream>>>(
        W3, dflag, W3T, HDIM, HDIM, HDIM, 0ull, 0ull);
    ftransp_k<<<dim3(HDIM / 64, NPAD4 / 64, 1), blk, 0, stream>>>(
        W4, dflag, W4T, HDIM, OUTN, NPAD4, 0ull, 0ull);

    gemm_f<<<dim3(MROWS / 128, HDIM / 128), blk, 0, stream>>>(
        xc, W1T, b1, 0ull, dflag, hA, 0ull, 0, nullptr, HDIM, KPAD1, 0, 0);

    for (int l = 0; l < LNUM; l++) {
      gemm_f<<<dim3(MROWS / 128, 3 * HDIM / 128), blk, 0, stream>>>(
          hA, sWT + (size_t)l * 3 * HDIM * HDIM, nullptr, 0ull, dflag,
          Ub, 0ull, 0, nullptr, 3 * HDIM, HDIM, 0, 0);
      sru_scan2_k<<<dim3((BB * HDIM) / 512), blk, 0, stream>>>(
          Ub, hA, hidden0, (unsigned long long)l * BB * HDIM,
          sru_b, (unsigned long long)l * 2 * HDIM,
          dflag, d_out, eo_hid + (unsigned long long)l * BB * HDIM);
    }

    gemm_f<<<dim3(MROWS / 128, HDIM / 128), blk, 0, stream>>>(
        hA, W3T, b3, 0ull, dflag, d_out, eo_fx, 2, y, HDIM, HDIM, TT, BB);

    gemm_f<<<dim3(MROWS / 128, NPAD4 / 128), blk, 0, stream>>>(
        y, W4T, b4, 0ull, dflag, d_out, 0ull, 2, nullptr, OUTN, HDIM, 0, 0);
  } else {
    const size_t need_f32U = z_flag + z_hA + z_U;
    const int u_f32 = (ws_size >= need_f32U) ? 1 : 0;
    void* U = (void*)Ubase;

    gemm_k<<<dim3(MROWS / BM, HDIM / BN), blk, 0, stream>>>(
        x, W1, b1, hA, 0ull, 0, nullptr, dflag, 0ull, 0ull,
        MROWS, HDIM, D_IN, BB, TT, 2);

    for (int l = 0; l < LNUM; l++) {
      gemm_k<<<dim3(MROWS / BM, (3 * HDIM) / BN), blk, 0, stream>>>(
          hA, sru_W, nullptr, U, 0ull, (u_f32 ? 1 : 0), nullptr, dflag,
          (unsigned long long)l * HDIM * 3 * HDIM, 0ull,
          MROWS, 3 * HDIM, HDIM, 0, 0, 0);
      sru_scan_k<<<dim3((BB * HDIM) / 256), blk, 0, stream>>>(
          U, u_f32, hA, hidden0, (unsigned long long)l * BB * HDIM,
          sru_b, (unsigned long long)l * 2 * HDIM,
          dflag, d_out, eo_hid + (unsigned long long)l * BB * HDIM);
    }

    gemm_k<<<dim3(MROWS / BM, HDIM / BN), blk, 0, stream>>>(
        hA, W3, b3, d_out, eo_fx, 2, y, dflag, 0ull, 0ull,
        MROWS, HDIM, HDIM, TT, BB, 0);

    gemm_k<<<dim3(MROWS / BM, (OUTN + BN - 1) / BN), blk, 0, stream>>>(
        y, W4, b4, d_out, 0ull, 2, nullptr, dflag, 0ull, 0ull,
        MROWS, OUTN, HDIM, 0, 0, 0);
  }
}